// Round 8
// baseline (515.866 us; speedup 1.0000x reference)
//
#include <hip/hip_runtime.h>
#include <cstdint>
#include <cstddef>

typedef unsigned short u16;
typedef __bf16 bf16x8 __attribute__((ext_vector_type(8)));
typedef __bf16 bf16x4 __attribute__((ext_vector_type(4)));
typedef float f32x4 __attribute__((ext_vector_type(4)));

// ---------- helpers ----------
__device__ __forceinline__ u16 f2bf(float f) {            // round-to-nearest-even
  unsigned u = __float_as_uint(f);
  u += 0x7fffu + ((u >> 16) & 1u);
  return (u16)(u >> 16);
}

__device__ __forceinline__ float block_sum(float v, float* sbuf, int tid) {
#pragma unroll
  for (int off = 1; off < 64; off <<= 1) v += __shfl_xor(v, off, 64);
  if ((tid & 63) == 0) sbuf[tid >> 6] = v;
  __syncthreads();
  v = sbuf[0] + sbuf[1] + sbuf[2] + sbuf[3];
  __syncthreads();
  return v;
}

// async global->LDS, 16B per lane; LDS dest = wave-uniform base + lane*16.
__device__ __forceinline__ void gld16(const void* g, void* l) {
  __builtin_amdgcn_global_load_lds((const __attribute__((address_space(1))) void*)g,
                                   (__attribute__((address_space(3))) void*)l,
                                   16, 0, 0);
}

// Tiled K layout: kt[z][tile][c=d/8][t=0..127][j=d%8]  (16KB/tile, MFMA B-frag image)
// Tiled V layout: vt[z][tile][tc=t/8][d=0..63][j=t%8]  (16KB/tile)

// =======================================================================
// Big-tile GEMM machinery: BMxBN tile, BK=64, 512 threads (8 waves),
// wave grid = 2Mx4N (BN=256) or 4Mx2N (BN=128); 64 cols per wave always.
// 2-phase double-buffer, counted vmcnt, raw s_barrier.
// LDS XOR swizzle both-sides: linear gld16 dest + inverse-swizzled GLOBAL
// source (chunk ^= row&7) + swizzled ds_read_b128.
// Bijective XCD swizzle, sid-linear (bx-fastest) -> each XCD owns a
// contiguous m-panel (A L2-resident; B shared via L3).
// 128x128 @ 64KB LDS -> 2 blocks/CU: co-resident block hides barrier drain.
// Measured: 128x128 2-phase ~632 TF (at the 2ph structural ceiling, m228d).
// =======================================================================

#define BIG_PREAMBLE(BM, BN, Kdim, KB)                                           \
  constexpr int NQA = (BM) / 64;                                                 \
  constexpr int NQB = (BN) / 64;                                                 \
  constexpr int WN  = ((BN) == 256) ? 4 : 2;                                     \
  constexpr int IF  = (BM) * WN / 128;                                           \
  const int tid = threadIdx.x;                                                   \
  const int lane = tid & 63, wave = tid >> 6;                                    \
  const int l15 = lane & 15, g = (lane >> 4) & 3;                                \
  const int wr = (wave / WN) * ((BM) * WN / 8), wc = (wave % WN) * 64;           \
  const int gx = gridDim.x;                                                      \
  const int nwg = gx * gridDim.y;                                                \
  const int id = blockIdx.y * gx + blockIdx.x;                                   \
  const int qq = nwg >> 3, rr = nwg & 7;                                         \
  const int xcd = id & 7, slot = id >> 3;                                        \
  const int sid = (xcd < rr ? xcd * (qq + 1) : rr * (qq + 1) + (xcd - rr) * qq) + slot; \
  const int bx = sid % gx, by = sid / gx;                                        \
  const int m0 = by * (BM), n0 = bx * (BN);                                      \
  size_t aoff[NQA]; int adst[NQA];                                               \
  size_t boff[NQB]; int bdst[NQB];                                               \
  _Pragma("unroll")                                                              \
  for (int q = 0; q < NQA; ++q) {                                                \
    const int c = tid + q * 512, row = c >> 3, ch = (c & 7) ^ (row & 7);         \
    aoff[q] = (size_t)(m0 + row) * (Kdim) + ch * 8 + (KB);                       \
    adst[q] = c * 8;                                                             \
  }                                                                              \
  _Pragma("unroll")                                                              \
  for (int q = 0; q < NQB; ++q) {                                                \
    const int c = tid + q * 512, row = c >> 3, ch = (c & 7) ^ (row & 7);         \
    boff[q] = (size_t)(n0 + row) * (Kdim) + ch * 8 + (KB);                       \
    bdst[q] = c * 8;                                                             \
  }

#define BIG_STAGE(BM, BN, kk, buf)                                               \
  {                                                                              \
    _Pragma("unroll")                                                            \
    for (int q = 0; q < NQA; ++q) gld16(A + aoff[q] + (kk), As + (buf) * ((BM) * 64) + adst[q]); \
    _Pragma("unroll")                                                            \
    for (int q = 0; q < NQB; ++q) gld16(B + boff[q] + (kk), Bs + (buf) * ((BN) * 64) + bdst[q]); \
  }

#define BIG_COMPUTE(BM, BN, buf)                                                 \
  {                                                                              \
    _Pragma("unroll")                                                            \
    for (int ks = 0; ks < 2; ++ks) {                                             \
      const int chR = (((ks * 4 + g) ^ (l15 & 7)) * 8);                          \
      bf16x8 af[IF], bg[4];                                                      \
      _Pragma("unroll")                                                          \
      for (int i = 0; i < IF; ++i)                                               \
        af[i] = *(const bf16x8*)(As + (buf) * ((BM) * 64) + (wr + i * 16 + l15) * 64 + chR); \
      _Pragma("unroll")                                                          \
      for (int j = 0; j < 4; ++j)                                                \
        bg[j] = *(const bf16x8*)(Bs + (buf) * ((BN) * 64) + (wc + j * 16 + l15) * 64 + chR); \
      _Pragma("unroll")                                                          \
      for (int i = 0; i < IF; ++i)                                               \
        _Pragma("unroll")                                                        \
        for (int j = 0; j < 4; ++j)                                              \
          acc[i][j] = __builtin_amdgcn_mfma_f32_16x16x32_bf16(af[i], bg[j], acc[i][j], 0, 0, 0); \
    }                                                                            \
  }

// vmcnt(N): N = loads issued per stage (NQA+NQB) -> previous stage fully landed.
#define BIG_WAIT_PREV()                                                          \
  if constexpr (NQA + NQB == 8)      asm volatile("s_waitcnt vmcnt(8)\ns_barrier" ::: "memory"); \
  else if constexpr (NQA + NQB == 6) asm volatile("s_waitcnt vmcnt(6)\ns_barrier" ::: "memory"); \
  else if constexpr (NQA + NQB == 5) asm volatile("s_waitcnt vmcnt(5)\ns_barrier" ::: "memory"); \
  else if constexpr (NQA + NQB == 4) asm volatile("s_waitcnt vmcnt(4)\ns_barrier" ::: "memory"); \
  else                               asm volatile("s_waitcnt vmcnt(3)\ns_barrier" ::: "memory");

#define BIG_KLOOP(BM, BN, NT)                                                    \
  f32x4 acc[IF][4] = {};                                                         \
  BIG_STAGE(BM, BN, 0, 0)                                                        \
  int cur = 0;                                                                   \
  for (int t = 0; t < (NT) - 1; ++t) {                                           \
    BIG_STAGE(BM, BN, (t + 1) * 64, cur ^ 1)                                     \
    BIG_WAIT_PREV()                                                              \
    BIG_COMPUTE(BM, BN, cur)                                                     \
    asm volatile("s_waitcnt lgkmcnt(0)\ns_barrier" ::: "memory");                \
    cur ^= 1;                                                                    \
  }                                                                              \
  asm volatile("s_waitcnt vmcnt(0)\ns_barrier" ::: "memory");                    \
  BIG_COMPUTE(BM, BN, cur)

// ---------- big-tile GEMM with bf16 epilogues ----------
// MODE 0: bias+GELU -> bf16 out0[gm*N+col]
// MODE 1: qkv scatter -> qh(out0, *0.125), kt(out1), vt(out2)
// MODE 3: kv scatter  -> kt(out1), vt(out2)
template<int BM, int BN, int MODE>
__global__ __launch_bounds__(512, 2) void gemm_big(
    const u16* __restrict__ A, const u16* __restrict__ B,
    const float* __restrict__ bias,
    u16* __restrict__ out0, u16* __restrict__ out1, u16* __restrict__ out2,
    int N, int K)
{
  __shared__ __align__(16) u16 As[2 * BM * 64];
  __shared__ __align__(16) u16 Bs[2 * BN * 64];
  BIG_PREAMBLE(BM, BN, K, 0)
  const int NT = K >> 6;
  BIG_KLOOP(BM, BN, NT)

  if constexpr (MODE == 0) {
#pragma unroll
    for (int i = 0; i < IF; ++i) {
#pragma unroll
      for (int j = 0; j < 4; ++j) {
        const int col = n0 + wc + j * 16 + l15;
        const float bs = bias[col];
#pragma unroll
        for (int r = 0; r < 4; ++r) {
          const int gm = m0 + wr + i * 16 + g * 4 + r;
          float v = acc[i][j][r] + bs;
          v = 0.5f * v * (1.0f + erff(v * 0.70710678118654752f));
          out0[(size_t)gm * N + col] = f2bf(v);
        }
      }
    }
  } else {
#pragma unroll
    for (int i = 0; i < IF; ++i) {
#pragma unroll
      for (int j = 0; j < 4; ++j) {
        const int col = n0 + wc + j * 16 + l15;
        const int sec = (n0 + wc + j * 16) >> 10;          // wave-uniform section
        const int tgt = (MODE == 1) ? sec : sec + 1;
        const float bs = bias[col];
#pragma unroll
        for (int r = 0; r < 4; ++r) {
          const int gm = m0 + wr + i * 16 + g * 4 + r;
          const float v = acc[i][j][r] + bs;
          const int cl = col & 1023, h = cl >> 6, d = cl & 63;
          const int z = (gm >> 10) * 16 + h, s = gm & 1023;
          if (tgt == 0)
            out0[((size_t)z * 1024 + s) * 64 + d] = f2bf(v * 0.125f);
          else if (tgt == 1)
            out1[((((size_t)z * 8 + (s >> 7)) * 8 + (d >> 3)) * 128 + (s & 127)) * 8 + (d & 7)] = f2bf(v);
          else
            out2[((size_t)z * 8 + (s >> 7)) * 8192 + (((s >> 3) & 15) * 64 + d) * 8 + (s & 7)] = f2bf(v);
        }
      }
    }
  }
}

// ---------- big-tile GEMM, fp32 out over K-range (N=1024) ----------
// z=1 (Klen==K): direct full-K fp32 result. z=2: split-K partials (unused now).
template<int BM, int BN>
__global__ __launch_bounds__(512, 2) void gemm_part(
    const u16* __restrict__ A, const u16* __restrict__ B,
    float* __restrict__ part, int K, int Klen)
{
  __shared__ __align__(16) u16 As[2 * BM * 64];
  __shared__ __align__(16) u16 Bs[2 * BN * 64];
  const int kb = blockIdx.z * Klen;
  float* outP = part + (size_t)blockIdx.z * (4096ULL * 1024);
  BIG_PREAMBLE(BM, BN, K, kb)
  const int NT = Klen >> 6;
  BIG_KLOOP(BM, BN, NT)

#pragma unroll
  for (int i = 0; i < IF; ++i)
#pragma unroll
    for (int j = 0; j < 4; ++j) {
      const int col = n0 + wc + j * 16 + l15;
#pragma unroll
      for (int r = 0; r < 4; ++r) {
        const int gm = m0 + wr + i * 16 + g * 4 + r;
        outP[(size_t)gm * 1024 + col] = acc[i][j][r];
      }
    }
}

// ---------- flash attention v5: swapped QK^T (T12), in-lane softmax ----------
// 64-row Q-blocks, 4 waves x 16 rows, 4 blocks/CU (LDS 40960).
// mfma(K,Q): A/B frags have identical lane images, so operand swap is free;
// P output [t][q=l15] -> each lane owns one q-row's 16 scores in-lane:
//   row-max/sum = in-lane tree + shfl_xor 16,32 (cross-g) -- 2 DS ops vs 16.
// m_i/l_i scalar per lane. T13 defer-rescale (THR=8, wave-uniform).
// sP[q][t] 64x64 bf16, XOR swizzle (byte ^= (l15&7)<<4) on b64 write / b128 read.
__global__ __launch_bounds__(256, 4) void flash_attn(
    const u16* __restrict__ qh, const u16* __restrict__ kt, const u16* __restrict__ vt,
    const float* __restrict__ emask, u16* __restrict__ ctx, int causal)
{
  __shared__ __align__(16) u16 sK[8192];
  __shared__ __align__(16) u16 sV[8192];
  __shared__ __align__(16) u16 sP[64 * 64];

  const int tid = threadIdx.x, lane = tid & 63, wave = tid >> 6;
  const int l15 = lane & 15, g = (lane >> 4) & 3;
  const int id = blockIdx.y * 8 + blockIdx.x;
  const int xcd = id & 7, slot = id >> 3;          // slot 0..127
  const int z = xcd * 8 + (slot >> 4), b = z >> 4, h = z & 15;
  const int q0 = (slot & 15) * 64;                 // 64-row q-subtile
  const int r0 = wave * 16;                        // wave's 16 rows
  const int qrel = q0 & 64;                        // row offset within 128-kv diagonal tile
  const int swzP = (l15 & 7) << 4;

  bf16x8 qf[2];
  {
    const u16* qz = qh + ((size_t)z * 1024 + q0 + r0 + l15) * 64 + g * 8;
#pragma unroll
    for (int kc = 0; kc < 2; ++kc)
      qf[kc] = *(const bf16x8*)(qz + kc * 32);
  }

  float m_i = -1.0e30f, l_i = 0.0f;
  f32x4 o[4] = {};
  const int dt = (q0 >> 7) << 7;                   // diagonal kv-tile start
  const int tmax = causal ? dt : 896;

  for (int t0 = 0; t0 <= tmax; t0 += 128) {
    const u16* ktile = kt + ((size_t)z * 8 + (t0 >> 7)) * 8192;
    const u16* vtile = vt + ((size_t)z * 8 + (t0 >> 7)) * 8192;
    __syncthreads();
#pragma unroll
    for (int i = 0; i < 4; ++i) {
      const int off = (wave * 4 + i) * 512 + lane * 8;
      gld16(ktile + off, sK + off);
      gld16(vtile + off, sV + off);
    }
    __syncthreads();

#pragma unroll
    for (int ci = 0; ci < 2; ++ci) {
      if (causal && t0 == dt && ci * 64 > qrel + r0 + 15) continue;

      // ---- QK^T, swapped operands: D[t][q=l15] ----
      f32x4 sa[4] = {};
#pragma unroll
      for (int kc = 0; kc < 2; ++kc) {
        bf16x8 bg[4];
#pragma unroll
        for (int jn = 0; jn < 4; ++jn)
          bg[jn] = *(const bf16x8*)(sK + ((kc * 4 + g) * 128 + ci * 64 + jn * 16 + l15) * 8);
#pragma unroll
        for (int jn = 0; jn < 4; ++jn)
          sa[jn] = __builtin_amdgcn_mfma_f32_16x16x32_bf16(bg[jn], qf[kc], sa[jn], 0, 0, 0);
      }

      // ---- mask ----
      if (causal) {
        if (t0 == dt && ci * 64 + 63 > qrel + r0) {
          const int qq = qrel + r0 + l15;
#pragma unroll
          for (int jn = 0; jn < 4; ++jn) {
#pragma unroll
            for (int r = 0; r < 4; ++r) {
              const int trel = ci * 64 + jn * 16 + g * 4 + r;
              if (trel > qq) sa[jn][r] = -3.0e38f;
            }
          }
        }
      } else {
#pragma unroll
        for (int jn = 0; jn < 4; ++jn) {
          const f32x4 me = *(const f32x4*)(emask + (size_t)b * 1024 + t0 + ci * 64 + jn * 16 + g * 4);
#pragma unroll
          for (int r = 0; r < 4; ++r) sa[jn][r] += me[r];
        }
      }

      // ---- in-lane row max (one q-row per lane) ----
      f32x4 m4;
#pragma unroll
      for (int r = 0; r < 4; ++r)
        m4[r] = fmaxf(fmaxf(sa[0][r], sa[1][r]), fmaxf(sa[2][r], sa[3][r]));
      float pmax = fmaxf(fmaxf(m4[0], m4[1]), fmaxf(m4[2], m4[3]));
      pmax = fmaxf(pmax, __shfl_xor(pmax, 16, 64));
      pmax = fmaxf(pmax, __shfl_xor(pmax, 32, 64));

      // ---- T13 defer-rescale ----
      if (!__all(pmax <= m_i + 8.0f)) {
        const float mn = fmaxf(m_i, pmax);
        const float al = __expf(m_i - mn);
        m_i = mn;
        l_i *= al;
#pragma unroll
        for (int r = 0; r < 4; ++r) {
          const float ar = __shfl(al, g * 4 + r, 16);
#pragma unroll
          for (int jn = 0; jn < 4; ++jn) o[jn][r] *= ar;
        }
      }

      // ---- P = exp(sa - m_i), in-lane sum, pack to sP ----
      f32x4 p[4];
#pragma unroll
      for (int jn = 0; jn < 4; ++jn)
#pragma unroll
        for (int r = 0; r < 4; ++r)
          p[jn][r] = __expf(sa[jn][r] - m_i);
      f32x4 s4;
#pragma unroll
      for (int r = 0; r < 4; ++r)
        s4[r] = (p[0][r] + p[1][r]) + (p[2][r] + p[3][r]);
      float s = (s4[0] + s4[1]) + (s4[2] + s4[3]);
      s += __shfl_xor(s, 16, 64);
      s += __shfl_xor(s, 32, 64);
      l_i += s;

#pragma unroll
      for (int jn = 0; jn < 4; ++jn) {
        bf16x4 pk;
#pragma unroll
        for (int r = 0; r < 4; ++r) pk[r] = (__bf16)p[jn][r];
        *(bf16x4*)(sP + (((r0 + l15) * 128 + ((jn * 32 + g * 8) ^ swzP)) >> 1)) = pk;
      }

      asm volatile("s_waitcnt lgkmcnt(0)" ::: "memory");

      // ---- PV ----
#pragma unroll
      for (int kc2 = 0; kc2 < 2; ++kc2) {
        const bf16x8 pa = *(const bf16x8*)(sP + (((r0 + l15) * 128 + ((kc2 * 64 + g * 16) ^ swzP)) >> 1));
        bf16x8 vb[4];
#pragma unroll
        for (int jn = 0; jn < 4; ++jn)
          vb[jn] = *(const bf16x8*)(sV + ((ci * 8 + kc2 * 4 + g) * 64 + jn * 16 + l15) * 8);
#pragma unroll
        for (int jn = 0; jn < 4; ++jn)
          o[jn] = __builtin_amdgcn_mfma_f32_16x16x32_bf16(pa, vb[jn], o[jn], 0, 0, 0);
      }
    }
  }

#pragma unroll
  for (int r = 0; r < 4; ++r) {
    const float inv = 1.0f / __shfl(l_i, g * 4 + r, 16);
    const size_t base = ((size_t)(b * 1024 + q0 + r0 + g * 4 + r)) * 1024 + h * 64;
#pragma unroll
    for (int jn = 0; jn < 4; ++jn)
      ctx[base + jn * 16 + l15] = f2bf(o[jn][r] * inv);
  }
}

// ---------- mega prep: 7 weight transposes + enc cvt + LN1 in one launch ----------
struct PrepArgs {
  const float* w[7]; u16* wt[7]; int K[7]; int N[7]; int cum[7];
  const float* enc; u16* enc_bf;
  const float* hid; const float* ln1w; const float* ln1b; u16* xln;
};
__global__ __launch_bounds__(256) void prep_kernel(PrepArgs a) {
  __shared__ float t[32][33];
  __shared__ float sbuf[4];
  const int bb = blockIdx.x, tid = threadIdx.x;
  if (bb < 16384) {
    int wi = 0;
#pragma unroll
    for (int i = 0; i < 7; ++i) if (bb >= a.cum[i]) wi = i + 1; else break;
    const int base = wi ? a.cum[wi - 1] : 0;
    const int tileIdx = bb - base;
    const int Kd = a.K[wi], Nd = a.N[wi], nx = Nd >> 5;
    const int n0 = (tileIdx % nx) * 32, k0 = (tileIdx / nx) * 32;
    const float* w = a.w[wi]; u16* wt = a.wt[wi];
    const int tx = tid & 31, ty = tid >> 5;
#pragma unroll
    for (int r = ty; r < 32; r += 8) t[r][tx] = w[(size_t)(k0 + r) * Nd + n0 + tx];
    __syncthreads();
#pragma unroll
    for (int r = ty; r < 32; r += 8) wt[(size_t)(n0 + r) * Kd + k0 + tx] = f2bf(t[tx][r]);
  } else if (bb < 20480) {
    const size_t i = ((size_t)(bb - 16384) * 256 + tid) * 4;
    const float4 v = *(const float4*)(a.enc + i);
    ushort4 o; o.x = f2bf(v.x); o.y = f2bf(v.y); o.z = f2bf(v.z); o.w = f2bf(v.w);
    *(ushort4*)(a.enc_bf + i) = o;
  } else {
    const int row = bb - 20480;
    const float4 v = *(const float4*)(a.hid + (size_t)row * 1024 + tid * 4);
    float s = block_sum(v.x + v.y + v.z + v.w, sbuf, tid);
    const float u = s * (1.0f / 1024.0f);
    const float d0 = v.x - u, d1 = v.y - u, d2 = v.z - u, d3 = v.w - u;
    float sq = block_sum(d0 * d0 + d1 * d1 + d2 * d2 + d3 * d3, sbuf, tid);
    const float rstd = rsqrtf(sq * (1.0f / 1024.0f) + 1e-12f);
    const int c = tid * 4;
    ushort4 o;
    o.x = f2bf(a.ln1w[c + 0] * d0 * rstd + a.ln1b[c + 0]);
    o.y = f2bf(a.ln1w[c + 1] * d1 * rstd + a.ln1b[c + 1]);
    o.z = f2bf(a.ln1w[c + 2] * d2 * rstd + a.ln1b[c + 2]);
    o.w = f2bf(a.ln1w[c + 3] * d3 * rstd + a.ln1b[c + 3]);
    *(ushort4*)(a.xln + (size_t)row * 1024 + c) = o;
  }
}

// ---------- reducers ----------
__global__ __launch_bounds__(256) void ln_red1_kernel(
    const float* __restrict__ p0,
    const float* __restrict__ bias, const float* __restrict__ res,
    const float* __restrict__ w, const float* __restrict__ b,
    float* __restrict__ hOut, u16* __restrict__ xln)
{
  __shared__ float sbuf[4];
  const int row = blockIdx.x, tid = threadIdx.x;
  const size_t off = (size_t)row * 1024 + tid * 4;
  const int c = tid * 4;
  const float4 a0 = *(const float4*)(p0 + off);
  const float4 bs = *(const float4*)(bias + c);
  const float4 rs = *(const float4*)(res + off);
  float4 v;
  v.x = a0.x + bs.x + rs.x;
  v.y = a0.y + bs.y + rs.y;
  v.z = a0.z + bs.z + rs.z;
  v.w = a0.w + bs.w + rs.w;
  *(float4*)(hOut + off) = v;
  float s = block_sum(v.x + v.y + v.z + v.w, sbuf, tid);
  const float u = s * (1.0f / 1024.0f);
  const float d0 = v.x - u, d1 = v.y - u, d2 = v.z - u, d3 = v.w - u;
  float sq = block_sum(d0 * d0 + d1 * d1 + d2 * d2 + d3 * d3, sbuf, tid);
  const float rstd = rsqrtf(sq * (1.0f / 1024.0f) + 1e-12f);
  ushort4 o;
  o.x = f2bf(w[c + 0] * d0 * rstd + b[c + 0]);
  o.y = f2bf(w[c + 1] * d1 * rstd + b[c + 1]);
  o.z = f2bf(w[c + 2] * d2 * rstd + b[c + 2]);
  o.w = f2bf(w[c + 3] * d3 * rstd + b[c + 3]);
  *(ushort4*)(xln + off) = o;
}

__global__ __launch_bounds__(256) void reduce_q1_kernel(
    const float* __restrict__ p0,
    const float* __restrict__ bias, u16* __restrict__ qh)
{
  const int m = blockIdx.x, tid = threadIdx.x;
  const size_t off = (size_t)m * 1024 + tid * 4;
  const int n = tid * 4, h = n >> 6, d = n & 63;
  const int b = m >> 10, s = m & 1023;
  const float4 a0 = *(const float4*)(p0 + off);
  const float4 bs = *(const float4*)(bias + n);
  ushort4 o;
  o.x = f2bf((a0.x + bs.x) * 0.125f);
  o.y = f2bf((a0.y + bs.y) * 0.125f);
  o.z = f2bf((a0.z + bs.z) * 0.125f);
  o.w = f2bf((a0.w + bs.w) * 0.125f);
  *(ushort4*)(qh + ((size_t)((b * 16 + h) * 1024 + s)) * 64 + d) = o;
}

// 1-way final reducer: full-K fp32 result + bias + residual -> fp32 out
__global__ __launch_bounds__(256) void reduce_out1_kernel(
    const float* __restrict__ p0,
    const float* __restrict__ bias, const float* __restrict__ res,
    float* __restrict__ out)
{
  const int m = blockIdx.x, tid = threadIdx.x;
  const size_t off = (size_t)m * 1024 + tid * 4;
  const int c = tid * 4;
  const float4 a0 = *(const float4*)(p0 + off);
  const float4 bs = *(const float4*)(bias + c);
  const float4 rs = *(const float4*)(res + off);
  float4 v;
  v.x = a0.x + bs.x + rs.x;
  v.y = a0.y + bs.y + rs.y;
  v.z = a0.z + bs.z + rs.z;
  v.w = a0.w + bs.w + rs.w;
  *(float4*)(out + off) = v;
}

// ---------- workspace layout (bytes) ----------
constexpr size_t MB = 1024ULL * 1024;
constexpr size_t WT_QKV    = 0;            // 6 MB
constexpr size_t WT_ATTN_O = 6 * MB;       // 2
constexpr size_t WT_Q      = 8 * MB;       // 2
constexpr size_t WT_KV     = 10 * MB;      // 4
constexpr size_t WT_CA_O   = 14 * MB;      // 2
constexpr size_t WT_FFN_IN = 16 * MB;      // 8
constexpr size_t WT_FFN_OUT= 24 * MB;      // 8
constexpr size_t ENC_BF    = 32 * MB;      // 8
constexpr size_t XLN       = 40 * MB;      // 8
constexpr size_t QH        = 48 * MB;      // 8
constexpr size_t KT        = 56 * MB;      // 8
constexpr size_t VT        = 64 * MB;      // 8
constexpr size_t CTX       = 72 * MB;      // 8
constexpr size_t HBUF      = 80 * MB;      // 16 (fp32 residual spine)
constexpr size_t SP0       = 96 * MB;      // 16 fp32 full-K result
constexpr size_t SP1       = 112 * MB;     // 16 (unused)
constexpr size_t FFN_MID   = 128 * MB;     // 32 bf16 [4096,4096]
// total 160 MB

extern "C" void kernel_launch(void* const* d_in, const int* in_sizes, int n_in,
                              void* d_out, int out_size, void* d_ws, size_t ws_size,
                              hipStream_t stream) {
  const float* hidden   = (const float*)d_in[0];
  const float* enc      = (const float*)d_in[1];
  const float* encm     = (const float*)d_in[2];
  const float* ln1w = (const float*)d_in[4],  *ln1b = (const float*)d_in[5];
  const float* qkv_w = (const float*)d_in[6], *qkv_b = (const float*)d_in[7];
  const float* attn_o_w = (const float*)d_in[8], *attn_o_b = (const float*)d_in[9];
  const float* ln2w = (const float*)d_in[10], *ln2b = (const float*)d_in[11];
  const float* q_w = (const float*)d_in[12],  *q_b = (const float*)d_in[13];
  const float* kv_w = (const float*)d_in[14], *kv_b = (const float*)d_in[15];
  const float* ca_o_w = (const float*)d_in[16], *ca_o_b = (const float*)d_in[17];
  const float* ln3w = (const float*)d_in[18], *ln3b = (const float*)d_in[19];
  const float* ffn_in_w = (const float*)d_in[20], *ffn_in_b = (const float*)d_in[21];
  const float* ffn_out_w = (const float*)d_in[22], *ffn_out_b = (const float*)d_in[23];

  char* ws = (char*)d_ws;
  u16* wt_qkv    = (u16*)(ws + WT_QKV);
  u16* wt_attn_o = (u16*)(ws + WT_ATTN_O);
  u16* wt_q      = (u16*)(ws + WT_Q);
  u16* wt_kv     = (u16*)(ws + WT_KV);
  u16* wt_ca_o   = (u16*)(ws + WT_CA_O);
  u16* wt_ffn_in = (u16*)(ws + WT_FFN_IN);
  u16* wt_ffn_out= (u16*)(ws + WT_FFN_OUT);
  u16* enc_bf = (u16*)(ws + ENC_BF);
  u16* xln    = (u16*)(ws + XLN);
  u16* qh     = (u16*)(ws + QH);
  u16* kt     = (u16*)(ws + KT);
  u16* vt     = (u16*)(ws + VT);
  u16* ctx    = (u16*)(ws + CTX);
  float* hF   = (float*)(ws + HBUF);
  float* sp0  = (float*)(ws + SP0);
  u16* ffn_mid = (u16*)(ws + FFN_MID);

  // ---- prep: all weight transposes + enc cvt + LN1, one launch ----
  PrepArgs pa;
  pa.w[0] = qkv_w;    pa.wt[0] = wt_qkv;     pa.K[0] = 1024; pa.N[0] = 3072; pa.cum[0] = 3072;
  pa.w[1] = attn_o_w; pa.wt[1] = wt_attn_o;  pa.K[1] = 1024; pa.N[1] = 1024; pa.cum[1] = 4096;
  pa.w[2] = q_w;      pa.wt[2] = wt_q;       pa.K[2] = 1024; pa.N[2] = 1024; pa.cum[2] = 5120;
  pa.w[3] = kv_w;     pa.wt[3] = wt_kv;      pa.K[3] = 1024; pa.N[3] = 2048; pa.cum[3] = 7168;
  pa.w[4] = ca_o_w;   pa.wt[4] = wt_ca_o;    pa.K[4] = 1024; pa.N[4] = 1024; pa.cum[4] = 8192;
  pa.w[5] = ffn_in_w; pa.wt[5] = wt_ffn_in;  pa.K[5] = 1024; pa.N[5] = 4096; pa.cum[5] = 12288;
  pa.w[6] = ffn_out_w;pa.wt[6] = wt_ffn_out; pa.K[6] = 4096; pa.N[6] = 1024; pa.cum[6] = 16384;
  pa.enc = enc; pa.enc_bf = enc_bf;
  pa.hid = hidden; pa.ln1w = ln1w; pa.ln1b = ln1b; pa.xln = xln;
  prep_kernel<<<24576, 256, 0, stream>>>(pa);

  // ---- self-attention ----
  gemm_big<128, 128, 1><<<dim3(24, 32), 512, 0, stream>>>(xln, wt_qkv, qkv_b, qh, kt, vt, 3072, 1024);
  flash_attn<<<dim3(8, 128), 256, 0, stream>>>(qh, kt, vt, nullptr, ctx, 1);
  gemm_part<128, 128><<<dim3(8, 32, 1), 512, 0, stream>>>(ctx, wt_attn_o, sp0, 1024, 1024);
  ln_red1_kernel<<<4096, 256, 0, stream>>>(sp0, attn_o_b, hidden, ln2w, ln2b, hF, xln);

  // ---- cross-attention ----
  gemm_part<128, 128><<<dim3(8, 32, 1), 512, 0, stream>>>(xln, wt_q, sp0, 1024, 1024);
  reduce_q1_kernel<<<4096, 256, 0, stream>>>(sp0, q_b, qh);
  gemm_big<128, 128, 3><<<dim3(16, 32), 512, 0, stream>>>(enc_bf, wt_kv, kv_b, nullptr, kt, vt, 2048, 1024);
  flash_attn<<<dim3(8, 128), 256, 0, stream>>>(qh, kt, vt, encm, ctx, 0);
  gemm_part<128, 128><<<dim3(8, 32, 1), 512, 0, stream>>>(ctx, wt_ca_o, sp0, 1024, 1024);
  ln_red1_kernel<<<4096, 256, 0, stream>>>(sp0, ca_o_b, hF, ln3w, ln3b, hF, xln);

  // ---- FFN ----
  gemm_big<128, 128, 0><<<dim3(32, 32), 512, 0, stream>>>(xln, wt_ffn_in, ffn_in_b, ffn_mid, nullptr, nullptr, 4096, 1024);
  gemm_part<128, 128><<<dim3(8, 32, 1), 512, 0, stream>>>(ffn_mid, wt_ffn_out, sp0, 4096, 4096);
  reduce_out1_kernel<<<4096, 256, 0, stream>>>(sp0, ffn_out_b, hF, (float*)d_out);
}

// Round 10
// 507.555 us; speedup vs baseline: 1.0164x; 1.0164x over previous
//
#include <hip/hip_runtime.h>
#include <cstdint>
#include <cstddef>

typedef unsigned short u16;
typedef __bf16 bf16x8 __attribute__((ext_vector_type(8)));
typedef __bf16 bf16x4 __attribute__((ext_vector_type(4)));
typedef float f32x4 __attribute__((ext_vector_type(4)));

// ---------- helpers ----------
__device__ __forceinline__ u16 f2bf(float f) {            // round-to-nearest-even
  unsigned u = __float_as_uint(f);
  u += 0x7fffu + ((u >> 16) & 1u);
  return (u16)(u >> 16);
}

__device__ __forceinline__ float block_sum(float v, float* sbuf, int tid) {
#pragma unroll
  for (int off = 1; off < 64; off <<= 1) v += __shfl_xor(v, off, 64);
  if ((tid & 63) == 0) sbuf[tid >> 6] = v;
  __syncthreads();
  v = sbuf[0] + sbuf[1] + sbuf[2] + sbuf[3];
  __syncthreads();
  return v;
}

// async global->LDS, 16B per lane; LDS dest = wave-uniform base + lane*16.
__device__ __forceinline__ void gld16(const void* g, void* l) {
  __builtin_amdgcn_global_load_lds((const __attribute__((address_space(1))) void*)g,
                                   (__attribute__((address_space(3))) void*)l,
                                   16, 0, 0);
}

// Tiled K layout: kt[z][tile][c=d/8][t=0..127][j=d%8]  (16KB/tile, MFMA B-frag image)
// Tiled V layout: vt[z][tile][tc=t/8][d=0..63][j=t%8]  (16KB/tile)

// =======================================================================
// Big-tile GEMM machinery: BMxBN tile, BK=64, 512 threads (8 waves),
// wave grid = 2Mx4N (BN=256) or 4Mx2N (BN=128); 64 cols per wave always.
// 2-phase double-buffer, counted vmcnt, raw s_barrier.
// LDS XOR swizzle both-sides: linear gld16 dest + inverse-swizzled GLOBAL
// source (chunk ^= row&7) + swizzled ds_read_b128.
// Bijective XCD swizzle, sid-linear (bx-fastest) -> each XCD owns a
// contiguous m-panel (A L2-resident; B shared via L3).
// CO-RESIDENCY RULE (measured r5/r6/r8): the 2-phase drain is only hidden
// when >=2 blocks/CU are resident -> grid MUST exceed 256 blocks.
//   128x128 @ 64KB -> 2/CU (needs grid >= 512)
//   64x128  @ 48KB -> 3/CU (grid 512 for N=1024 GEMMs)
// =======================================================================

#define BIG_PREAMBLE(BM, BN, Kdim, KB)                                           \
  constexpr int NQA = (BM) / 64;                                                 \
  constexpr int NQB = (BN) / 64;                                                 \
  constexpr int WN  = ((BN) == 256) ? 4 : 2;                                     \
  constexpr int IF  = (BM) * WN / 128;                                           \
  const int tid = threadIdx.x;                                                   \
  const int lane = tid & 63, wave = tid >> 6;                                    \
  const int l15 = lane & 15, g = (lane >> 4) & 3;                                \
  const int wr = (wave / WN) * ((BM) * WN / 8), wc = (wave % WN) * 64;           \
  const int gx = gridDim.x;                                                      \
  const int nwg = gx * gridDim.y;                                                \
  const int id = blockIdx.y * gx + blockIdx.x;                                   \
  const int qq = nwg >> 3, rr = nwg & 7;                                         \
  const int xcd = id & 7, slot = id >> 3;                                        \
  const int sid = (xcd < rr ? xcd * (qq + 1) : rr * (qq + 1) + (xcd - rr) * qq) + slot; \
  const int bx = sid % gx, by = sid / gx;                                        \
  const int m0 = by * (BM), n0 = bx * (BN);                                      \
  size_t aoff[NQA]; int adst[NQA];                                               \
  size_t boff[NQB]; int bdst[NQB];                                               \
  _Pragma("unroll")                                                              \
  for (int q = 0; q < NQA; ++q) {                                                \
    const int c = tid + q * 512, row = c >> 3, ch = (c & 7) ^ (row & 7);         \
    aoff[q] = (size_t)(m0 + row) * (Kdim) + ch * 8 + (KB);                       \
    adst[q] = c * 8;                                                             \
  }                                                                              \
  _Pragma("unroll")                                                              \
  for (int q = 0; q < NQB; ++q) {                                                \
    const int c = tid + q * 512, row = c >> 3, ch = (c & 7) ^ (row & 7);         \
    boff[q] = (size_t)(n0 + row) * (Kdim) + ch * 8 + (KB);                       \
    bdst[q] = c * 8;                                                             \
  }

#define BIG_STAGE(BM, BN, kk, buf)                                               \
  {                                                                              \
    _Pragma("unroll")                                                            \
    for (int q = 0; q < NQA; ++q) gld16(A + aoff[q] + (kk), As + (buf) * ((BM) * 64) + adst[q]); \
    _Pragma("unroll")                                                            \
    for (int q = 0; q < NQB; ++q) gld16(B + boff[q] + (kk), Bs + (buf) * ((BN) * 64) + bdst[q]); \
  }

#define BIG_COMPUTE(BM, BN, buf)                                                 \
  {                                                                              \
    _Pragma("unroll")                                                            \
    for (int ks = 0; ks < 2; ++ks) {                                             \
      const int chR = (((ks * 4 + g) ^ (l15 & 7)) * 8);                          \
      bf16x8 af[IF], bg[4];                                                      \
      _Pragma("unroll")                                                          \
      for (int i = 0; i < IF; ++i)                                               \
        af[i] = *(const bf16x8*)(As + (buf) * ((BM) * 64) + (wr + i * 16 + l15) * 64 + chR); \
      _Pragma("unroll")                                                          \
      for (int j = 0; j < 4; ++j)                                                \
        bg[j] = *(const bf16x8*)(Bs + (buf) * ((BN) * 64) + (wc + j * 16 + l15) * 64 + chR); \
      _Pragma("unroll")                                                          \
      for (int i = 0; i < IF; ++i)                                               \
        _Pragma("unroll")                                                        \
        for (int j = 0; j < 4; ++j)                                              \
          acc[i][j] = __builtin_amdgcn_mfma_f32_16x16x32_bf16(af[i], bg[j], acc[i][j], 0, 0, 0); \
    }                                                                            \
  }

// vmcnt(N): N = loads issued per stage (NQA+NQB) -> previous stage fully landed.
#define BIG_WAIT_PREV()                                                          \
  if constexpr (NQA + NQB == 8)      asm volatile("s_waitcnt vmcnt(8)\ns_barrier" ::: "memory"); \
  else if constexpr (NQA + NQB == 6) asm volatile("s_waitcnt vmcnt(6)\ns_barrier" ::: "memory"); \
  else if constexpr (NQA + NQB == 5) asm volatile("s_waitcnt vmcnt(5)\ns_barrier" ::: "memory"); \
  else if constexpr (NQA + NQB == 4) asm volatile("s_waitcnt vmcnt(4)\ns_barrier" ::: "memory"); \
  else                               asm volatile("s_waitcnt vmcnt(3)\ns_barrier" ::: "memory");

#define BIG_KLOOP(BM, BN, NT)                                                    \
  f32x4 acc[IF][4] = {};                                                         \
  BIG_STAGE(BM, BN, 0, 0)                                                        \
  int cur = 0;                                                                   \
  for (int t = 0; t < (NT) - 1; ++t) {                                           \
    BIG_STAGE(BM, BN, (t + 1) * 64, cur ^ 1)                                     \
    BIG_WAIT_PREV()                                                              \
    BIG_COMPUTE(BM, BN, cur)                                                     \
    asm volatile("s_waitcnt lgkmcnt(0)\ns_barrier" ::: "memory");                \
    cur ^= 1;                                                                    \
  }                                                                              \
  asm volatile("s_waitcnt vmcnt(0)\ns_barrier" ::: "memory");                    \
  BIG_COMPUTE(BM, BN, cur)

// ---------- big-tile GEMM with bf16 epilogues ----------
// MODE 0: bias+GELU -> bf16 out0[gm*N+col]
// MODE 1: qkv scatter -> qh(out0, *0.125), kt(out1), vt(out2)
// MODE 3: kv scatter  -> kt(out1), vt(out2)
template<int BM, int BN, int MODE>
__global__ __launch_bounds__(512, 2) void gemm_big(
    const u16* __restrict__ A, const u16* __restrict__ B,
    const float* __restrict__ bias,
    u16* __restrict__ out0, u16* __restrict__ out1, u16* __restrict__ out2,
    int N, int K)
{
  __shared__ __align__(16) u16 As[2 * BM * 64];
  __shared__ __align__(16) u16 Bs[2 * BN * 64];
  BIG_PREAMBLE(BM, BN, K, 0)
  const int NT = K >> 6;
  BIG_KLOOP(BM, BN, NT)

  if constexpr (MODE == 0) {
#pragma unroll
    for (int i = 0; i < IF; ++i) {
#pragma unroll
      for (int j = 0; j < 4; ++j) {
        const int col = n0 + wc + j * 16 + l15;
        const float bs = bias[col];
#pragma unroll
        for (int r = 0; r < 4; ++r) {
          const int gm = m0 + wr + i * 16 + g * 4 + r;
          float v = acc[i][j][r] + bs;
          v = 0.5f * v * (1.0f + erff(v * 0.70710678118654752f));
          out0[(size_t)gm * N + col] = f2bf(v);
        }
      }
    }
  } else {
#pragma unroll
    for (int i = 0; i < IF; ++i) {
#pragma unroll
      for (int j = 0; j < 4; ++j) {
        const int col = n0 + wc + j * 16 + l15;
        const int sec = (n0 + wc + j * 16) >> 10;          // wave-uniform section
        const int tgt = (MODE == 1) ? sec : sec + 1;
        const float bs = bias[col];
#pragma unroll
        for (int r = 0; r < 4; ++r) {
          const int gm = m0 + wr + i * 16 + g * 4 + r;
          const float v = acc[i][j][r] + bs;
          const int cl = col & 1023, h = cl >> 6, d = cl & 63;
          const int z = (gm >> 10) * 16 + h, s = gm & 1023;
          if (tgt == 0)
            out0[((size_t)z * 1024 + s) * 64 + d] = f2bf(v * 0.125f);
          else if (tgt == 1)
            out1[((((size_t)z * 8 + (s >> 7)) * 8 + (d >> 3)) * 128 + (s & 127)) * 8 + (d & 7)] = f2bf(v);
          else
            out2[((size_t)z * 8 + (s >> 7)) * 8192 + (((s >> 3) & 15) * 64 + d) * 8 + (s & 7)] = f2bf(v);
        }
      }
    }
  }
}

// ---------- big-tile GEMM, fp32 out over K-range (N=1024) ----------
// z=1 (Klen==K): direct full-K fp32 result.
template<int BM, int BN>
__global__ __launch_bounds__(512, 2) void gemm_part(
    const u16* __restrict__ A, const u16* __restrict__ B,
    float* __restrict__ part, int K, int Klen)
{
  __shared__ __align__(16) u16 As[2 * BM * 64];
  __shared__ __align__(16) u16 Bs[2 * BN * 64];
  const int kb = blockIdx.z * Klen;
  float* outP = part + (size_t)blockIdx.z * (4096ULL * 1024);
  BIG_PREAMBLE(BM, BN, K, kb)
  const int NT = Klen >> 6;
  BIG_KLOOP(BM, BN, NT)

#pragma unroll
  for (int i = 0; i < IF; ++i)
#pragma unroll
    for (int j = 0; j < 4; ++j) {
      const int col = n0 + wc + j * 16 + l15;
#pragma unroll
      for (int r = 0; r < 4; ++r) {
        const int gm = m0 + wr + i * 16 + g * 4 + r;
        outP[(size_t)gm * 1024 + col] = acc[i][j][r];
      }
    }
}

// ---------- flash attention v5: swapped QK^T (T12), in-lane softmax ----------
// 64-row Q-blocks, 4 waves x 16 rows, 4 blocks/CU (LDS 40960).
// mfma(K,Q): A/B frags have identical lane images, so operand swap is free;
// P output [t][q=l15] -> each lane owns one q-row's 16 scores in-lane:
//   row-max/sum = in-lane tree + shfl_xor 16,32 (cross-g) -- 2 DS ops vs 16.
// m_i/l_i scalar per lane. T13 defer-rescale (THR=8, wave-uniform).
// sP[q][t] 64x64 bf16, XOR swizzle (byte ^= (l15&7)<<4) on b64 write / b128 read.
__global__ __launch_bounds__(256, 4) void flash_attn(
    const u16* __restrict__ qh, const u16* __restrict__ kt, const u16* __restrict__ vt,
    const float* __restrict__ emask, u16* __restrict__ ctx, int causal)
{
  __shared__ __align__(16) u16 sK[8192];
  __shared__ __align__(16) u16 sV[8192];
  __shared__ __align__(16) u16 sP[64 * 64];

  const int tid = threadIdx.x, lane = tid & 63, wave = tid >> 6;
  const int l15 = lane & 15, g = (lane >> 4) & 3;
  const int id = blockIdx.y * 8 + blockIdx.x;
  const int xcd = id & 7, slot = id >> 3;          // slot 0..127
  const int z = xcd * 8 + (slot >> 4), b = z >> 4, h = z & 15;
  const int q0 = (slot & 15) * 64;                 // 64-row q-subtile
  const int r0 = wave * 16;                        // wave's 16 rows
  const int qrel = q0 & 64;                        // row offset within 128-kv diagonal tile
  const int swzP = (l15 & 7) << 4;

  bf16x8 qf[2];
  {
    const u16* qz = qh + ((size_t)z * 1024 + q0 + r0 + l15) * 64 + g * 8;
#pragma unroll
    for (int kc = 0; kc < 2; ++kc)
      qf[kc] = *(const bf16x8*)(qz + kc * 32);
  }

  float m_i = -1.0e30f, l_i = 0.0f;
  f32x4 o[4] = {};
  const int dt = (q0 >> 7) << 7;                   // diagonal kv-tile start
  const int tmax = causal ? dt : 896;

  for (int t0 = 0; t0 <= tmax; t0 += 128) {
    const u16* ktile = kt + ((size_t)z * 8 + (t0 >> 7)) * 8192;
    const u16* vtile = vt + ((size_t)z * 8 + (t0 >> 7)) * 8192;
    __syncthreads();
#pragma unroll
    for (int i = 0; i < 4; ++i) {
      const int off = (wave * 4 + i) * 512 + lane * 8;
      gld16(ktile + off, sK + off);
      gld16(vtile + off, sV + off);
    }
    __syncthreads();

#pragma unroll
    for (int ci = 0; ci < 2; ++ci) {
      if (causal && t0 == dt && ci * 64 > qrel + r0 + 15) continue;

      // ---- QK^T, swapped operands: D[t][q=l15] ----
      f32x4 sa[4] = {};
#pragma unroll
      for (int kc = 0; kc < 2; ++kc) {
        bf16x8 bg[4];
#pragma unroll
        for (int jn = 0; jn < 4; ++jn)
          bg[jn] = *(const bf16x8*)(sK + ((kc * 4 + g) * 128 + ci * 64 + jn * 16 + l15) * 8);
#pragma unroll
        for (int jn = 0; jn < 4; ++jn)
          sa[jn] = __builtin_amdgcn_mfma_f32_16x16x32_bf16(bg[jn], qf[kc], sa[jn], 0, 0, 0);
      }

      // ---- mask ----
      if (causal) {
        if (t0 == dt && ci * 64 + 63 > qrel + r0) {
          const int qq = qrel + r0 + l15;
#pragma unroll
          for (int jn = 0; jn < 4; ++jn) {
#pragma unroll
            for (int r = 0; r < 4; ++r) {
              const int trel = ci * 64 + jn * 16 + g * 4 + r;
              if (trel > qq) sa[jn][r] = -3.0e38f;
            }
          }
        }
      } else {
#pragma unroll
        for (int jn = 0; jn < 4; ++jn) {
          const f32x4 me = *(const f32x4*)(emask + (size_t)b * 1024 + t0 + ci * 64 + jn * 16 + g * 4);
#pragma unroll
          for (int r = 0; r < 4; ++r) sa[jn][r] += me[r];
        }
      }

      // ---- in-lane row max (one q-row per lane) ----
      f32x4 m4;
#pragma unroll
      for (int r = 0; r < 4; ++r)
        m4[r] = fmaxf(fmaxf(sa[0][r], sa[1][r]), fmaxf(sa[2][r], sa[3][r]));
      float pmax = fmaxf(fmaxf(m4[0], m4[1]), fmaxf(m4[2], m4[3]));
      pmax = fmaxf(pmax, __shfl_xor(pmax, 16, 64));
      pmax = fmaxf(pmax, __shfl_xor(pmax, 32, 64));

      // ---- T13 defer-rescale ----
      if (!__all(pmax <= m_i + 8.0f)) {
        const float mn = fmaxf(m_i, pmax);
        const float al = __expf(m_i - mn);
        m_i = mn;
        l_i *= al;
#pragma unroll
        for (int r = 0; r < 4; ++r) {
          const float ar = __shfl(al, g * 4 + r, 16);
#pragma unroll
          for (int jn = 0; jn < 4; ++jn) o[jn][r] *= ar;
        }
      }

      // ---- P = exp(sa - m_i), in-lane sum, pack to sP ----
      f32x4 p[4];
#pragma unroll
      for (int jn = 0; jn < 4; ++jn)
#pragma unroll
        for (int r = 0; r < 4; ++r)
          p[jn][r] = __expf(sa[jn][r] - m_i);
      f32x4 s4;
#pragma unroll
      for (int r = 0; r < 4; ++r)
        s4[r] = (p[0][r] + p[1][r]) + (p[2][r] + p[3][r]);
      float s = (s4[0] + s4[1]) + (s4[2] + s4[3]);
      s += __shfl_xor(s, 16, 64);
      s += __shfl_xor(s, 32, 64);
      l_i += s;

#pragma unroll
      for (int jn = 0; jn < 4; ++jn) {
        bf16x4 pk;
#pragma unroll
        for (int r = 0; r < 4; ++r) pk[r] = (__bf16)p[jn][r];
        *(bf16x4*)(sP + (((r0 + l15) * 128 + ((jn * 32 + g * 8) ^ swzP)) >> 1)) = pk;
      }

      asm volatile("s_waitcnt lgkmcnt(0)" ::: "memory");

      // ---- PV ----
#pragma unroll
      for (int kc2 = 0; kc2 < 2; ++kc2) {
        const bf16x8 pa = *(const bf16x8*)(sP + (((r0 + l15) * 128 + ((kc2 * 64 + g * 16) ^ swzP)) >> 1));
        bf16x8 vb[4];
#pragma unroll
        for (int jn = 0; jn < 4; ++jn)
          vb[jn] = *(const bf16x8*)(sV + ((ci * 8 + kc2 * 4 + g) * 64 + jn * 16 + l15) * 8);
#pragma unroll
        for (int jn = 0; jn < 4; ++jn)
          o[jn] = __builtin_amdgcn_mfma_f32_16x16x32_bf16(pa, vb[jn], o[jn], 0, 0, 0);
      }
    }
  }

#pragma unroll
  for (int r = 0; r < 4; ++r) {
    const float inv = 1.0f / __shfl(l_i, g * 4 + r, 16);
    const size_t base = ((size_t)(b * 1024 + q0 + r0 + g * 4 + r)) * 1024 + h * 64;
#pragma unroll
    for (int jn = 0; jn < 4; ++jn)
      ctx[base + jn * 16 + l15] = f2bf(o[jn][r] * inv);
  }
}

// ---------- mega prep: 7 weight transposes + enc cvt + LN1 in one launch ----------
struct PrepArgs {
  const float* w[7]; u16* wt[7]; int K[7]; int N[7]; int cum[7];
  const float* enc; u16* enc_bf;
  const float* hid; const float* ln1w; const float* ln1b; u16* xln;
};
__global__ __launch_bounds__(256) void prep_kernel(PrepArgs a) {
  __shared__ float t[32][33];
  __shared__ float sbuf[4];
  const int bb = blockIdx.x, tid = threadIdx.x;
  if (bb < 16384) {
    int wi = 0;
#pragma unroll
    for (int i = 0; i < 7; ++i) if (bb >= a.cum[i]) wi = i + 1; else break;
    const int base = wi ? a.cum[wi - 1] : 0;
    const int tileIdx = bb - base;
    const int Kd = a.K[wi], Nd = a.N[wi], nx = Nd >> 5;
    const int n0 = (tileIdx % nx) * 32, k0 = (tileIdx / nx) * 32;
    const float* w = a.w[wi]; u16* wt = a.wt[wi];
    const int tx = tid & 31, ty = tid >> 5;
#pragma unroll
    for (int r = ty; r < 32; r += 8) t[r][tx] = w[(size_t)(k0 + r) * Nd + n0 + tx];
    __syncthreads();
#pragma unroll
    for (int r = ty; r < 32; r += 8) wt[(size_t)(n0 + r) * Kd + k0 + tx] = f2bf(t[tx][r]);
  } else if (bb < 20480) {
    const size_t i = ((size_t)(bb - 16384) * 256 + tid) * 4;
    const float4 v = *(const float4*)(a.enc + i);
    ushort4 o; o.x = f2bf(v.x); o.y = f2bf(v.y); o.z = f2bf(v.z); o.w = f2bf(v.w);
    *(ushort4*)(a.enc_bf + i) = o;
  } else {
    const int row = bb - 20480;
    const float4 v = *(const float4*)(a.hid + (size_t)row * 1024 + tid * 4);
    float s = block_sum(v.x + v.y + v.z + v.w, sbuf, tid);
    const float u = s * (1.0f / 1024.0f);
    const float d0 = v.x - u, d1 = v.y - u, d2 = v.z - u, d3 = v.w - u;
    float sq = block_sum(d0 * d0 + d1 * d1 + d2 * d2 + d3 * d3, sbuf, tid);
    const float rstd = rsqrtf(sq * (1.0f / 1024.0f) + 1e-12f);
    const int c = tid * 4;
    ushort4 o;
    o.x = f2bf(a.ln1w[c + 0] * d0 * rstd + a.ln1b[c + 0]);
    o.y = f2bf(a.ln1w[c + 1] * d1 * rstd + a.ln1b[c + 1]);
    o.z = f2bf(a.ln1w[c + 2] * d2 * rstd + a.ln1b[c + 2]);
    o.w = f2bf(a.ln1w[c + 3] * d3 * rstd + a.ln1b[c + 3]);
    *(ushort4*)(a.xln + (size_t)row * 1024 + c) = o;
  }
}

// ---------- reducers ----------
__global__ __launch_bounds__(256) void ln_red1_kernel(
    const float* __restrict__ p0,
    const float* __restrict__ bias, const float* __restrict__ res,
    const float* __restrict__ w, const float* __restrict__ b,
    float* __restrict__ hOut, u16* __restrict__ xln)
{
  __shared__ float sbuf[4];
  const int row = blockIdx.x, tid = threadIdx.x;
  const size_t off = (size_t)row * 1024 + tid * 4;
  const int c = tid * 4;
  const float4 a0 = *(const float4*)(p0 + off);
  const float4 bs = *(const float4*)(bias + c);
  const float4 rs = *(const float4*)(res + off);
  float4 v;
  v.x = a0.x + bs.x + rs.x;
  v.y = a0.y + bs.y + rs.y;
  v.z = a0.z + bs.z + rs.z;
  v.w = a0.w + bs.w + rs.w;
  *(float4*)(hOut + off) = v;
  float s = block_sum(v.x + v.y + v.z + v.w, sbuf, tid);
  const float u = s * (1.0f / 1024.0f);
  const float d0 = v.x - u, d1 = v.y - u, d2 = v.z - u, d3 = v.w - u;
  float sq = block_sum(d0 * d0 + d1 * d1 + d2 * d2 + d3 * d3, sbuf, tid);
  const float rstd = rsqrtf(sq * (1.0f / 1024.0f) + 1e-12f);
  ushort4 o;
  o.x = f2bf(w[c + 0] * d0 * rstd + b[c + 0]);
  o.y = f2bf(w[c + 1] * d1 * rstd + b[c + 1]);
  o.z = f2bf(w[c + 2] * d2 * rstd + b[c + 2]);
  o.w = f2bf(w[c + 3] * d3 * rstd + b[c + 3]);
  *(ushort4*)(xln + off) = o;
}

__global__ __launch_bounds__(256) void reduce_q1_kernel(
    const float* __restrict__ p0,
    const float* __restrict__ bias, u16* __restrict__ qh)
{
  const int m = blockIdx.x, tid = threadIdx.x;
  const size_t off = (size_t)m * 1024 + tid * 4;
  const int n = tid * 4, h = n >> 6, d = n & 63;
  const int b = m >> 10, s = m & 1023;
  const float4 a0 = *(const float4*)(p0 + off);
  const float4 bs = *(const float4*)(bias + n);
  ushort4 o;
  o.x = f2bf((a0.x + bs.x) * 0.125f);
  o.y = f2bf((a0.y + bs.y) * 0.125f);
  o.z = f2bf((a0.z + bs.z) * 0.125f);
  o.w = f2bf((a0.w + bs.w) * 0.125f);
  *(ushort4*)(qh + ((size_t)((b * 16 + h) * 1024 + s)) * 64 + d) = o;
}

// 1-way final reducer: full-K fp32 result + bias + residual -> fp32 out
__global__ __launch_bounds__(256) void reduce_out1_kernel(
    const float* __restrict__ p0,
    const float* __restrict__ bias, const float* __restrict__ res,
    float* __restrict__ out)
{
  const int m = blockIdx.x, tid = threadIdx.x;
  const size_t off = (size_t)m * 1024 + tid * 4;
  const int c = tid * 4;
  const float4 a0 = *(const float4*)(p0 + off);
  const float4 bs = *(const float4*)(bias + c);
  const float4 rs = *(const float4*)(res + off);
  float4 v;
  v.x = a0.x + bs.x + rs.x;
  v.y = a0.y + bs.y + rs.y;
  v.z = a0.z + bs.z + rs.z;
  v.w = a0.w + bs.w + rs.w;
  *(float4*)(out + off) = v;
}

// ---------- workspace layout (bytes) ----------
constexpr size_t MB = 1024ULL * 1024;
constexpr size_t WT_QKV    = 0;            // 6 MB
constexpr size_t WT_ATTN_O = 6 * MB;       // 2
constexpr size_t WT_Q      = 8 * MB;       // 2
constexpr size_t WT_KV     = 10 * MB;      // 4
constexpr size_t WT_CA_O   = 14 * MB;      // 2
constexpr size_t WT_FFN_IN = 16 * MB;      // 8
constexpr size_t WT_FFN_OUT= 24 * MB;      // 8
constexpr size_t ENC_BF    = 32 * MB;      // 8
constexpr size_t XLN       = 40 * MB;      // 8
constexpr size_t QH        = 48 * MB;      // 8
constexpr size_t KT        = 56 * MB;      // 8
constexpr size_t VT        = 64 * MB;      // 8
constexpr size_t CTX       = 72 * MB;      // 8
constexpr size_t HBUF      = 80 * MB;      // 16 (fp32 residual spine)
constexpr size_t SP0       = 96 * MB;      // 16 fp32 full-K result
constexpr size_t SP1       = 112 * MB;     // 16 (unused)
constexpr size_t FFN_MID   = 128 * MB;     // 32 bf16 [4096,4096]
// total 160 MB

extern "C" void kernel_launch(void* const* d_in, const int* in_sizes, int n_in,
                              void* d_out, int out_size, void* d_ws, size_t ws_size,
                              hipStream_t stream) {
  const float* hidden   = (const float*)d_in[0];
  const float* enc      = (const float*)d_in[1];
  const float* encm     = (const float*)d_in[2];
  const float* ln1w = (const float*)d_in[4],  *ln1b = (const float*)d_in[5];
  const float* qkv_w = (const float*)d_in[6], *qkv_b = (const float*)d_in[7];
  const float* attn_o_w = (const float*)d_in[8], *attn_o_b = (const float*)d_in[9];
  const float* ln2w = (const float*)d_in[10], *ln2b = (const float*)d_in[11];
  const float* q_w = (const float*)d_in[12],  *q_b = (const float*)d_in[13];
  const float* kv_w = (const float*)d_in[14], *kv_b = (const float*)d_in[15];
  const float* ca_o_w = (const float*)d_in[16], *ca_o_b = (const float*)d_in[17];
  const float* ln3w = (const float*)d_in[18], *ln3b = (const float*)d_in[19];
  const float* ffn_in_w = (const float*)d_in[20], *ffn_in_b = (const float*)d_in[21];
  const float* ffn_out_w = (const float*)d_in[22], *ffn_out_b = (const float*)d_in[23];

  char* ws = (char*)d_ws;
  u16* wt_qkv    = (u16*)(ws + WT_QKV);
  u16* wt_attn_o = (u16*)(ws + WT_ATTN_O);
  u16* wt_q      = (u16*)(ws + WT_Q);
  u16* wt_kv     = (u16*)(ws + WT_KV);
  u16* wt_ca_o   = (u16*)(ws + WT_CA_O);
  u16* wt_ffn_in = (u16*)(ws + WT_FFN_IN);
  u16* wt_ffn_out= (u16*)(ws + WT_FFN_OUT);
  u16* enc_bf = (u16*)(ws + ENC_BF);
  u16* xln    = (u16*)(ws + XLN);
  u16* qh     = (u16*)(ws + QH);
  u16* kt     = (u16*)(ws + KT);
  u16* vt     = (u16*)(ws + VT);
  u16* ctx    = (u16*)(ws + CTX);
  float* hF   = (float*)(ws + HBUF);
  float* sp0  = (float*)(ws + SP0);
  u16* ffn_mid = (u16*)(ws + FFN_MID);

  // ---- prep: all weight transposes + enc cvt + LN1, one launch ----
  PrepArgs pa;
  pa.w[0] = qkv_w;    pa.wt[0] = wt_qkv;     pa.K[0] = 1024; pa.N[0] = 3072; pa.cum[0] = 3072;
  pa.w[1] = attn_o_w; pa.wt[1] = wt_attn_o;  pa.K[1] = 1024; pa.N[1] = 1024; pa.cum[1] = 4096;
  pa.w[2] = q_w;      pa.wt[2] = wt_q;       pa.K[2] = 1024; pa.N[2] = 1024; pa.cum[2] = 5120;
  pa.w[3] = kv_w;     pa.wt[3] = wt_kv;      pa.K[3] = 1024; pa.N[3] = 2048; pa.cum[3] = 7168;
  pa.w[4] = ca_o_w;   pa.wt[4] = wt_ca_o;    pa.K[4] = 1024; pa.N[4] = 1024; pa.cum[4] = 8192;
  pa.w[5] = ffn_in_w; pa.wt[5] = wt_ffn_in;  pa.K[5] = 1024; pa.N[5] = 4096; pa.cum[5] = 12288;
  pa.w[6] = ffn_out_w;pa.wt[6] = wt_ffn_out; pa.K[6] = 4096; pa.N[6] = 1024; pa.cum[6] = 16384;
  pa.enc = enc; pa.enc_bf = enc_bf;
  pa.hid = hidden; pa.ln1w = ln1w; pa.ln1b = ln1b; pa.xln = xln;
  prep_kernel<<<24576, 256, 0, stream>>>(pa);

  // ---- self-attention ----
  gemm_big<128, 128, 1><<<dim3(24, 32), 512, 0, stream>>>(xln, wt_qkv, qkv_b, qh, kt, vt, 3072, 1024);
  flash_attn<<<dim3(8, 128), 256, 0, stream>>>(qh, kt, vt, nullptr, ctx, 1);
  gemm_part<64, 128><<<dim3(8, 64, 1), 512, 0, stream>>>(ctx, wt_attn_o, sp0, 1024, 1024);
  ln_red1_kernel<<<4096, 256, 0, stream>>>(sp0, attn_o_b, hidden, ln2w, ln2b, hF, xln);

  // ---- cross-attention ----
  gemm_part<64, 128><<<dim3(8, 64, 1), 512, 0, stream>>>(xln, wt_q, sp0, 1024, 1024);
  reduce_q1_kernel<<<4096, 256, 0, stream>>>(sp0, q_b, qh);
  gemm_big<128, 128, 3><<<dim3(16, 32), 512, 0, stream>>>(enc_bf, wt_kv, kv_b, nullptr, kt, vt, 2048, 1024);
  flash_attn<<<dim3(8, 128), 256, 0, stream>>>(qh, kt, vt, encm, ctx, 0);
  gemm_part<64, 128><<<dim3(8, 64, 1), 512, 0, stream>>>(ctx, wt_ca_o, sp0, 1024, 1024);
  ln_red1_kernel<<<4096, 256, 0, stream>>>(sp0, ca_o_b, hF, ln3w, ln3b, hF, xln);

  // ---- FFN ----
  gemm_big<128, 128, 0><<<dim3(32, 32), 512, 0, stream>>>(xln, wt_ffn_in, ffn_in_b, ffn_mid, nullptr, nullptr, 4096, 1024);
  gemm_part<64, 128><<<dim3(8, 64, 1), 512, 0, stream>>>(ffn_mid, wt_ffn_out, sp0, 4096, 4096);
  reduce_out1_kernel<<<4096, 256, 0, stream>>>(sp0, ffn_out_b, hF, (float*)d_out);
}

// Round 11
// 484.394 us; speedup vs baseline: 1.0650x; 1.0478x over previous
//
#include <hip/hip_runtime.h>
#include <cstdint>
#include <cstddef>

typedef unsigned short u16;
typedef __bf16 bf16x8 __attribute__((ext_vector_type(8)));
typedef __bf16 bf16x4 __attribute__((ext_vector_type(4)));
typedef float f32x4 __attribute__((ext_vector_type(4)));

// ---------- helpers ----------
__device__ __forceinline__ u16 f2bf(float f) {            // round-to-nearest-even
  unsigned u = __float_as_uint(f);
  u += 0x7fffu + ((u >> 16) & 1u);
  return (u16)(u >> 16);
}

__device__ __forceinline__ float block_sum(float v, float* sbuf, int tid) {
#pragma unroll
  for (int off = 1; off < 64; off <<= 1) v += __shfl_xor(v, off, 64);
  if ((tid & 63) == 0) sbuf[tid >> 6] = v;
  __syncthreads();
  v = sbuf[0] + sbuf[1] + sbuf[2] + sbuf[3];
  __syncthreads();
  return v;
}

// async global->LDS, 16B per lane; LDS dest = wave-uniform base + lane*16.
__device__ __forceinline__ void gld16(const void* g, void* l) {
  __builtin_amdgcn_global_load_lds((const __attribute__((address_space(1))) void*)g,
                                   (__attribute__((address_space(3))) void*)l,
                                   16, 0, 0);
}

// Tiled K layout: kt[z][tile][c=d/8][t=0..127][j=d%8]  (16KB/tile, MFMA B-frag image)
// Tiled V layout: vt[z][tile][tc=t/8][d=0..63][j=t%8]  (16KB/tile)

// =======================================================================
// Big-tile GEMM machinery: BMxBN tile, BK=64, 512 threads (8 waves),
// wave grid = 2Mx4N (BN=256) or 4Mx2N (BN=128); 64 cols per wave always.
// 2-phase double-buffer, counted vmcnt, raw s_barrier.
// LDS XOR swizzle both-sides: linear gld16 dest + inverse-swizzled GLOBAL
// source (chunk ^= row&7) + swizzled ds_read_b128.
// Bijective XCD swizzle, sid-linear (bx-fastest) -> each XCD owns a
// contiguous m-panel (A L2-resident; B shared via L3).
// CO-RESIDENCY RULE (measured r5/r6/r8): the 2-phase drain is only hidden
// when >=2 blocks/CU are resident -> grid MUST exceed 256 blocks.
//   128x128 @ 64KB -> 2/CU (needs grid >= 512)
//   64x128  @ 48KB -> 3/CU (grid 512 for N=1024 GEMMs)
// Known ceilings (measured): 128x128 ~632 TF (MfmaUtil ~24, ds_read-bound),
// 64x128 ~614 TF (IF=1 thin tile, LDS-read-bound). Past this: 8-phase.
// =======================================================================

#define BIG_PREAMBLE(BM, BN, Kdim, KB)                                           \
  constexpr int NQA = (BM) / 64;                                                 \
  constexpr int NQB = (BN) / 64;                                                 \
  constexpr int WN  = ((BN) == 256) ? 4 : 2;                                     \
  constexpr int IF  = (BM) * WN / 128;                                           \
  const int tid = threadIdx.x;                                                   \
  const int lane = tid & 63, wave = tid >> 6;                                    \
  const int l15 = lane & 15, g = (lane >> 4) & 3;                                \
  const int wr = (wave / WN) * ((BM) * WN / 8), wc = (wave % WN) * 64;           \
  const int gx = gridDim.x;                                                      \
  const int nwg = gx * gridDim.y;                                                \
  const int id = blockIdx.y * gx + blockIdx.x;                                   \
  const int qq = nwg >> 3, rr = nwg & 7;                                         \
  const int xcd = id & 7, slot = id >> 3;                                        \
  const int sid = (xcd < rr ? xcd * (qq + 1) : rr * (qq + 1) + (xcd - rr) * qq) + slot; \
  const int bx = sid % gx, by = sid / gx;                                        \
  const int m0 = by * (BM), n0 = bx * (BN);                                      \
  size_t aoff[NQA]; int adst[NQA];                                               \
  size_t boff[NQB]; int bdst[NQB];                                               \
  _Pragma("unroll")                                                              \
  for (int q = 0; q < NQA; ++q) {                                                \
    const int c = tid + q * 512, row = c >> 3, ch = (c & 7) ^ (row & 7);         \
    aoff[q] = (size_t)(m0 + row) * (Kdim) + ch * 8 + (KB);                       \
    adst[q] = c * 8;                                                             \
  }                                                                              \
  _Pragma("unroll")                                                              \
  for (int q = 0; q < NQB; ++q) {                                                \
    const int c = tid + q * 512, row = c >> 3, ch = (c & 7) ^ (row & 7);         \
    boff[q] = (size_t)(n0 + row) * (Kdim) + ch * 8 + (KB);                       \
    bdst[q] = c * 8;                                                             \
  }

#define BIG_STAGE(BM, BN, kk, buf)                                               \
  {                                                                              \
    _Pragma("unroll")                                                            \
    for (int q = 0; q < NQA; ++q) gld16(A + aoff[q] + (kk), As + (buf) * ((BM) * 64) + adst[q]); \
    _Pragma("unroll")                                                            \
    for (int q = 0; q < NQB; ++q) gld16(B + boff[q] + (kk), Bs + (buf) * ((BN) * 64) + bdst[q]); \
  }

#define BIG_COMPUTE(BM, BN, buf)                                                 \
  {                                                                              \
    _Pragma("unroll")                                                            \
    for (int ks = 0; ks < 2; ++ks) {                                             \
      const int chR = (((ks * 4 + g) ^ (l15 & 7)) * 8);                          \
      bf16x8 af[IF], bg[4];                                                      \
      _Pragma("unroll")                                                          \
      for (int i = 0; i < IF; ++i)                                               \
        af[i] = *(const bf16x8*)(As + (buf) * ((BM) * 64) + (wr + i * 16 + l15) * 64 + chR); \
      _Pragma("unroll")                                                          \
      for (int j = 0; j < 4; ++j)                                                \
        bg[j] = *(const bf16x8*)(Bs + (buf) * ((BN) * 64) + (wc + j * 16 + l15) * 64 + chR); \
      _Pragma("unroll")                                                          \
      for (int i = 0; i < IF; ++i)                                               \
        _Pragma("unroll")                                                        \
        for (int j = 0; j < 4; ++j)                                              \
          acc[i][j] = __builtin_amdgcn_mfma_f32_16x16x32_bf16(af[i], bg[j], acc[i][j], 0, 0, 0); \
    }                                                                            \
  }

// vmcnt(N): N = loads issued per stage (NQA+NQB) -> previous stage fully landed.
#define BIG_WAIT_PREV()                                                          \
  if constexpr (NQA + NQB == 8)      asm volatile("s_waitcnt vmcnt(8)\ns_barrier" ::: "memory"); \
  else if constexpr (NQA + NQB == 6) asm volatile("s_waitcnt vmcnt(6)\ns_barrier" ::: "memory"); \
  else if constexpr (NQA + NQB == 5) asm volatile("s_waitcnt vmcnt(5)\ns_barrier" ::: "memory"); \
  else if constexpr (NQA + NQB == 4) asm volatile("s_waitcnt vmcnt(4)\ns_barrier" ::: "memory"); \
  else                               asm volatile("s_waitcnt vmcnt(3)\ns_barrier" ::: "memory");

#define BIG_KLOOP(BM, BN, NT)                                                    \
  f32x4 acc[IF][4] = {};                                                         \
  BIG_STAGE(BM, BN, 0, 0)                                                        \
  int cur = 0;                                                                   \
  for (int t = 0; t < (NT) - 1; ++t) {                                           \
    BIG_STAGE(BM, BN, (t + 1) * 64, cur ^ 1)                                     \
    BIG_WAIT_PREV()                                                              \
    BIG_COMPUTE(BM, BN, cur)                                                     \
    asm volatile("s_waitcnt lgkmcnt(0)\ns_barrier" ::: "memory");                \
    cur ^= 1;                                                                    \
  }                                                                              \
  asm volatile("s_waitcnt vmcnt(0)\ns_barrier" ::: "memory");                    \
  BIG_COMPUTE(BM, BN, cur)

// ---------- big-tile GEMM with bf16 epilogues ----------
// MODE 0: bias+GELU -> bf16 out0[gm*N+col]
// MODE 1: qkv scatter -> qh(out0, *0.125), kt(out1), vt(out2)
// MODE 3: kv scatter  -> kt(out1), vt(out2)
template<int BM, int BN, int MODE>
__global__ __launch_bounds__(512, 2) void gemm_big(
    const u16* __restrict__ A, const u16* __restrict__ B,
    const float* __restrict__ bias,
    u16* __restrict__ out0, u16* __restrict__ out1, u16* __restrict__ out2,
    int N, int K)
{
  __shared__ __align__(16) u16 As[2 * BM * 64];
  __shared__ __align__(16) u16 Bs[2 * BN * 64];
  BIG_PREAMBLE(BM, BN, K, 0)
  const int NT = K >> 6;
  BIG_KLOOP(BM, BN, NT)

  if constexpr (MODE == 0) {
#pragma unroll
    for (int i = 0; i < IF; ++i) {
#pragma unroll
      for (int j = 0; j < 4; ++j) {
        const int col = n0 + wc + j * 16 + l15;
        const float bs = bias[col];
#pragma unroll
        for (int r = 0; r < 4; ++r) {
          const int gm = m0 + wr + i * 16 + g * 4 + r;
          float v = acc[i][j][r] + bs;
          v = 0.5f * v * (1.0f + erff(v * 0.70710678118654752f));
          out0[(size_t)gm * N + col] = f2bf(v);
        }
      }
    }
  } else {
#pragma unroll
    for (int i = 0; i < IF; ++i) {
#pragma unroll
      for (int j = 0; j < 4; ++j) {
        const int col = n0 + wc + j * 16 + l15;
        const int sec = (n0 + wc + j * 16) >> 10;          // wave-uniform section
        const int tgt = (MODE == 1) ? sec : sec + 1;
        const float bs = bias[col];
#pragma unroll
        for (int r = 0; r < 4; ++r) {
          const int gm = m0 + wr + i * 16 + g * 4 + r;
          const float v = acc[i][j][r] + bs;
          const int cl = col & 1023, h = cl >> 6, d = cl & 63;
          const int z = (gm >> 10) * 16 + h, s = gm & 1023;
          if (tgt == 0)
            out0[((size_t)z * 1024 + s) * 64 + d] = f2bf(v * 0.125f);
          else if (tgt == 1)
            out1[((((size_t)z * 8 + (s >> 7)) * 8 + (d >> 3)) * 128 + (s & 127)) * 8 + (d & 7)] = f2bf(v);
          else
            out2[((size_t)z * 8 + (s >> 7)) * 8192 + (((s >> 3) & 15) * 64 + d) * 8 + (s & 7)] = f2bf(v);
        }
      }
    }
  }
}

// ---------- N=1024 GEMM (M=4096, full K) with fused reducer epilogues ----------
// MODE 0: raw fp32 -> outF[gm*1024+col]                  (attn_o, ca_o -> ln_red1)
// MODE 1: (acc+bias)*0.125 -> bf16 qh head-scatter       (q; replaces reduce_q1)
// MODE 2: acc+bias+res -> fp32 outF (final layer output) (ffn_out; replaces reduce_out1)
template<int BM, int BN, int MODE>
__global__ __launch_bounds__(512, 2) void gemm_n1024(
    const u16* __restrict__ A, const u16* __restrict__ B,
    const float* __restrict__ bias, const float* __restrict__ res,
    float* __restrict__ outF, u16* __restrict__ qh, int K)
{
  __shared__ __align__(16) u16 As[2 * BM * 64];
  __shared__ __align__(16) u16 Bs[2 * BN * 64];
  BIG_PREAMBLE(BM, BN, K, 0)
  const int NT = K >> 6;
  BIG_KLOOP(BM, BN, NT)

#pragma unroll
  for (int i = 0; i < IF; ++i)
#pragma unroll
    for (int j = 0; j < 4; ++j) {
      const int col = n0 + wc + j * 16 + l15;
      float bs = 0.0f;
      if constexpr (MODE != 0) bs = bias[col];
#pragma unroll
      for (int r = 0; r < 4; ++r) {
        const int gm = m0 + wr + i * 16 + g * 4 + r;
        if constexpr (MODE == 0) {
          outF[(size_t)gm * 1024 + col] = acc[i][j][r];
        } else if constexpr (MODE == 1) {
          const int b = gm >> 10, s = gm & 1023, h = col >> 6, d = col & 63;
          qh[(((size_t)(b * 16 + h) * 1024 + s)) * 64 + d] = f2bf((acc[i][j][r] + bs) * 0.125f);
        } else {
          const size_t off = (size_t)gm * 1024 + col;
          outF[off] = acc[i][j][r] + bs + res[off];
        }
      }
    }
}

// ---------- flash attention v5: swapped QK^T (T12), in-lane softmax ----------
// 64-row Q-blocks, 4 waves x 16 rows, 4 blocks/CU (LDS 40960).
// mfma(K,Q): A/B frags have identical lane images, so operand swap is free;
// P output [t][q=l15] -> each lane owns one q-row's 16 scores in-lane:
//   row-max/sum = in-lane tree + shfl_xor 16,32 (cross-g) -- 2 DS ops vs 16.
// m_i/l_i scalar per lane. T13 defer-rescale (THR=8, wave-uniform).
// sP[q][t] 64x64 bf16, XOR swizzle (byte ^= (l15&7)<<4) on b64 write / b128 read.
__global__ __launch_bounds__(256, 4) void flash_attn(
    const u16* __restrict__ qh, const u16* __restrict__ kt, const u16* __restrict__ vt,
    const float* __restrict__ emask, u16* __restrict__ ctx, int causal)
{
  __shared__ __align__(16) u16 sK[8192];
  __shared__ __align__(16) u16 sV[8192];
  __shared__ __align__(16) u16 sP[64 * 64];

  const int tid = threadIdx.x, lane = tid & 63, wave = tid >> 6;
  const int l15 = lane & 15, g = (lane >> 4) & 3;
  const int id = blockIdx.y * 8 + blockIdx.x;
  const int xcd = id & 7, slot = id >> 3;          // slot 0..127
  const int z = xcd * 8 + (slot >> 4), b = z >> 4, h = z & 15;
  const int q0 = (slot & 15) * 64;                 // 64-row q-subtile
  const int r0 = wave * 16;                        // wave's 16 rows
  const int qrel = q0 & 64;                        // row offset within 128-kv diagonal tile
  const int swzP = (l15 & 7) << 4;

  bf16x8 qf[2];
  {
    const u16* qz = qh + ((size_t)z * 1024 + q0 + r0 + l15) * 64 + g * 8;
#pragma unroll
    for (int kc = 0; kc < 2; ++kc)
      qf[kc] = *(const bf16x8*)(qz + kc * 32);
  }

  float m_i = -1.0e30f, l_i = 0.0f;
  f32x4 o[4] = {};
  const int dt = (q0 >> 7) << 7;                   // diagonal kv-tile start
  const int tmax = causal ? dt : 896;

  for (int t0 = 0; t0 <= tmax; t0 += 128) {
    const u16* ktile = kt + ((size_t)z * 8 + (t0 >> 7)) * 8192;
    const u16* vtile = vt + ((size_t)z * 8 + (t0 >> 7)) * 8192;
    __syncthreads();
#pragma unroll
    for (int i = 0; i < 4; ++i) {
      const int off = (wave * 4 + i) * 512 + lane * 8;
      gld16(ktile + off, sK + off);
      gld16(vtile + off, sV + off);
    }
    __syncthreads();

#pragma unroll
    for (int ci = 0; ci < 2; ++ci) {
      if (causal && t0 == dt && ci * 64 > qrel + r0 + 15) continue;

      // ---- QK^T, swapped operands: D[t][q=l15] ----
      f32x4 sa[4] = {};
#pragma unroll
      for (int kc = 0; kc < 2; ++kc) {
        bf16x8 bg[4];
#pragma unroll
        for (int jn = 0; jn < 4; ++jn)
          bg[jn] = *(const bf16x8*)(sK + ((kc * 4 + g) * 128 + ci * 64 + jn * 16 + l15) * 8);
#pragma unroll
        for (int jn = 0; jn < 4; ++jn)
          sa[jn] = __builtin_amdgcn_mfma_f32_16x16x32_bf16(bg[jn], qf[kc], sa[jn], 0, 0, 0);
      }

      // ---- mask ----
      if (causal) {
        if (t0 == dt && ci * 64 + 63 > qrel + r0) {
          const int qq = qrel + r0 + l15;
#pragma unroll
          for (int jn = 0; jn < 4; ++jn) {
#pragma unroll
            for (int r = 0; r < 4; ++r) {
              const int trel = ci * 64 + jn * 16 + g * 4 + r;
              if (trel > qq) sa[jn][r] = -3.0e38f;
            }
          }
        }
      } else {
#pragma unroll
        for (int jn = 0; jn < 4; ++jn) {
          const f32x4 me = *(const f32x4*)(emask + (size_t)b * 1024 + t0 + ci * 64 + jn * 16 + g * 4);
#pragma unroll
          for (int r = 0; r < 4; ++r) sa[jn][r] += me[r];
        }
      }

      // ---- in-lane row max (one q-row per lane) ----
      f32x4 m4;
#pragma unroll
      for (int r = 0; r < 4; ++r)
        m4[r] = fmaxf(fmaxf(sa[0][r], sa[1][r]), fmaxf(sa[2][r], sa[3][r]));
      float pmax = fmaxf(fmaxf(m4[0], m4[1]), fmaxf(m4[2], m4[3]));
      pmax = fmaxf(pmax, __shfl_xor(pmax, 16, 64));
      pmax = fmaxf(pmax, __shfl_xor(pmax, 32, 64));

      // ---- T13 defer-rescale ----
      if (!__all(pmax <= m_i + 8.0f)) {
        const float mn = fmaxf(m_i, pmax);
        const float al = __expf(m_i - mn);
        m_i = mn;
        l_i *= al;
#pragma unroll
        for (int r = 0; r < 4; ++r) {
          const float ar = __shfl(al, g * 4 + r, 16);
#pragma unroll
          for (int jn = 0; jn < 4; ++jn) o[jn][r] *= ar;
        }
      }

      // ---- P = exp(sa - m_i), in-lane sum, pack to sP ----
      f32x4 p[4];
#pragma unroll
      for (int jn = 0; jn < 4; ++jn)
#pragma unroll
        for (int r = 0; r < 4; ++r)
          p[jn][r] = __expf(sa[jn][r] - m_i);
      f32x4 s4;
#pragma unroll
      for (int r = 0; r < 4; ++r)
        s4[r] = (p[0][r] + p[1][r]) + (p[2][r] + p[3][r]);
      float s = (s4[0] + s4[1]) + (s4[2] + s4[3]);
      s += __shfl_xor(s, 16, 64);
      s += __shfl_xor(s, 32, 64);
      l_i += s;

#pragma unroll
      for (int jn = 0; jn < 4; ++jn) {
        bf16x4 pk;
#pragma unroll
        for (int r = 0; r < 4; ++r) pk[r] = (__bf16)p[jn][r];
        *(bf16x4*)(sP + (((r0 + l15) * 128 + ((jn * 32 + g * 8) ^ swzP)) >> 1)) = pk;
      }

      asm volatile("s_waitcnt lgkmcnt(0)" ::: "memory");

      // ---- PV ----
#pragma unroll
      for (int kc2 = 0; kc2 < 2; ++kc2) {
        const bf16x8 pa = *(const bf16x8*)(sP + (((r0 + l15) * 128 + ((kc2 * 64 + g * 16) ^ swzP)) >> 1));
        bf16x8 vb[4];
#pragma unroll
        for (int jn = 0; jn < 4; ++jn)
          vb[jn] = *(const bf16x8*)(sV + ((ci * 8 + kc2 * 4 + g) * 64 + jn * 16 + l15) * 8);
#pragma unroll
        for (int jn = 0; jn < 4; ++jn)
          o[jn] = __builtin_amdgcn_mfma_f32_16x16x32_bf16(pa, vb[jn], o[jn], 0, 0, 0);
      }
    }
  }

#pragma unroll
  for (int r = 0; r < 4; ++r) {
    const float inv = 1.0f / __shfl(l_i, g * 4 + r, 16);
    const size_t base = ((size_t)(b * 1024 + q0 + r0 + g * 4 + r)) * 1024 + h * 64;
#pragma unroll
    for (int jn = 0; jn < 4; ++jn)
      ctx[base + jn * 16 + l15] = f2bf(o[jn][r] * inv);
  }
}

// ---------- mega prep: 7 weight transposes + enc cvt + LN1 in one launch ----------
struct PrepArgs {
  const float* w[7]; u16* wt[7]; int K[7]; int N[7]; int cum[7];
  const float* enc; u16* enc_bf;
  const float* hid; const float* ln1w; const float* ln1b; u16* xln;
};
__global__ __launch_bounds__(256) void prep_kernel(PrepArgs a) {
  __shared__ float t[32][33];
  __shared__ float sbuf[4];
  const int bb = blockIdx.x, tid = threadIdx.x;
  if (bb < 16384) {
    int wi = 0;
#pragma unroll
    for (int i = 0; i < 7; ++i) if (bb >= a.cum[i]) wi = i + 1; else break;
    const int base = wi ? a.cum[wi - 1] : 0;
    const int tileIdx = bb - base;
    const int Kd = a.K[wi], Nd = a.N[wi], nx = Nd >> 5;
    const int n0 = (tileIdx % nx) * 32, k0 = (tileIdx / nx) * 32;
    const float* w = a.w[wi]; u16* wt = a.wt[wi];
    const int tx = tid & 31, ty = tid >> 5;
#pragma unroll
    for (int r = ty; r < 32; r += 8) t[r][tx] = w[(size_t)(k0 + r) * Nd + n0 + tx];
    __syncthreads();
#pragma unroll
    for (int r = ty; r < 32; r += 8) wt[(size_t)(n0 + r) * Kd + k0 + tx] = f2bf(t[tx][r]);
  } else if (bb < 20480) {
    const size_t i = ((size_t)(bb - 16384) * 256 + tid) * 4;
    const float4 v = *(const float4*)(a.enc + i);
    ushort4 o; o.x = f2bf(v.x); o.y = f2bf(v.y); o.z = f2bf(v.z); o.w = f2bf(v.w);
    *(ushort4*)(a.enc_bf + i) = o;
  } else {
    const int row = bb - 20480;
    const float4 v = *(const float4*)(a.hid + (size_t)row * 1024 + tid * 4);
    float s = block_sum(v.x + v.y + v.z + v.w, sbuf, tid);
    const float u = s * (1.0f / 1024.0f);
    const float d0 = v.x - u, d1 = v.y - u, d2 = v.z - u, d3 = v.w - u;
    float sq = block_sum(d0 * d0 + d1 * d1 + d2 * d2 + d3 * d3, sbuf, tid);
    const float rstd = rsqrtf(sq * (1.0f / 1024.0f) + 1e-12f);
    const int c = tid * 4;
    ushort4 o;
    o.x = f2bf(a.ln1w[c + 0] * d0 * rstd + a.ln1b[c + 0]);
    o.y = f2bf(a.ln1w[c + 1] * d1 * rstd + a.ln1b[c + 1]);
    o.z = f2bf(a.ln1w[c + 2] * d2 * rstd + a.ln1b[c + 2]);
    o.w = f2bf(a.ln1w[c + 3] * d3 * rstd + a.ln1b[c + 3]);
    *(ushort4*)(a.xln + (size_t)row * 1024 + c) = o;
  }
}

// ---------- reducers ----------
__global__ __launch_bounds__(256) void ln_red1_kernel(
    const float* __restrict__ p0,
    const float* __restrict__ bias, const float* __restrict__ res,
    const float* __restrict__ w, const float* __restrict__ b,
    float* __restrict__ hOut, u16* __restrict__ xln)
{
  __shared__ float sbuf[4];
  const int row = blockIdx.x, tid = threadIdx.x;
  const size_t off = (size_t)row * 1024 + tid * 4;
  const int c = tid * 4;
  const float4 a0 = *(const float4*)(p0 + off);
  const float4 bs = *(const float4*)(bias + c);
  const float4 rs = *(const float4*)(res + off);
  float4 v;
  v.x = a0.x + bs.x + rs.x;
  v.y = a0.y + bs.y + rs.y;
  v.z = a0.z + bs.z + rs.z;
  v.w = a0.w + bs.w + rs.w;
  *(float4*)(hOut + off) = v;
  float s = block_sum(v.x + v.y + v.z + v.w, sbuf, tid);
  const float u = s * (1.0f / 1024.0f);
  const float d0 = v.x - u, d1 = v.y - u, d2 = v.z - u, d3 = v.w - u;
  float sq = block_sum(d0 * d0 + d1 * d1 + d2 * d2 + d3 * d3, sbuf, tid);
  const float rstd = rsqrtf(sq * (1.0f / 1024.0f) + 1e-12f);
  ushort4 o;
  o.x = f2bf(w[c + 0] * d0 * rstd + b[c + 0]);
  o.y = f2bf(w[c + 1] * d1 * rstd + b[c + 1]);
  o.z = f2bf(w[c + 2] * d2 * rstd + b[c + 2]);
  o.w = f2bf(w[c + 3] * d3 * rstd + b[c + 3]);
  *(ushort4*)(xln + off) = o;
}

// ---------- workspace layout (bytes) ----------
constexpr size_t MB = 1024ULL * 1024;
constexpr size_t WT_QKV    = 0;            // 6 MB
constexpr size_t WT_ATTN_O = 6 * MB;       // 2
constexpr size_t WT_Q      = 8 * MB;       // 2
constexpr size_t WT_KV     = 10 * MB;      // 4
constexpr size_t WT_CA_O   = 14 * MB;      // 2
constexpr size_t WT_FFN_IN = 16 * MB;      // 8
constexpr size_t WT_FFN_OUT= 24 * MB;      // 8
constexpr size_t ENC_BF    = 32 * MB;      // 8
constexpr size_t XLN       = 40 * MB;      // 8
constexpr size_t QH        = 48 * MB;      // 8
constexpr size_t KT        = 56 * MB;      // 8
constexpr size_t VT        = 64 * MB;      // 8
constexpr size_t CTX       = 72 * MB;      // 8
constexpr size_t HBUF      = 80 * MB;      // 16 (fp32 residual spine)
constexpr size_t SP0       = 96 * MB;      // 16 fp32 full-K result
constexpr size_t SP1       = 112 * MB;     // 16 (unused)
constexpr size_t FFN_MID   = 128 * MB;     // 32 bf16 [4096,4096]
// total 160 MB

extern "C" void kernel_launch(void* const* d_in, const int* in_sizes, int n_in,
                              void* d_out, int out_size, void* d_ws, size_t ws_size,
                              hipStream_t stream) {
  const float* hidden   = (const float*)d_in[0];
  const float* enc      = (const float*)d_in[1];
  const float* encm     = (const float*)d_in[2];
  const float* ln1w = (const float*)d_in[4],  *ln1b = (const float*)d_in[5];
  const float* qkv_w = (const float*)d_in[6], *qkv_b = (const float*)d_in[7];
  const float* attn_o_w = (const float*)d_in[8], *attn_o_b = (const float*)d_in[9];
  const float* ln2w = (const float*)d_in[10], *ln2b = (const float*)d_in[11];
  const float* q_w = (const float*)d_in[12],  *q_b = (const float*)d_in[13];
  const float* kv_w = (const float*)d_in[14], *kv_b = (const float*)d_in[15];
  const float* ca_o_w = (const float*)d_in[16], *ca_o_b = (const float*)d_in[17];
  const float* ln3w = (const float*)d_in[18], *ln3b = (const float*)d_in[19];
  const float* ffn_in_w = (const float*)d_in[20], *ffn_in_b = (const float*)d_in[21];
  const float* ffn_out_w = (const float*)d_in[22], *ffn_out_b = (const float*)d_in[23];

  char* ws = (char*)d_ws;
  u16* wt_qkv    = (u16*)(ws + WT_QKV);
  u16* wt_attn_o = (u16*)(ws + WT_ATTN_O);
  u16* wt_q      = (u16*)(ws + WT_Q);
  u16* wt_kv     = (u16*)(ws + WT_KV);
  u16* wt_ca_o   = (u16*)(ws + WT_CA_O);
  u16* wt_ffn_in = (u16*)(ws + WT_FFN_IN);
  u16* wt_ffn_out= (u16*)(ws + WT_FFN_OUT);
  u16* enc_bf = (u16*)(ws + ENC_BF);
  u16* xln    = (u16*)(ws + XLN);
  u16* qh     = (u16*)(ws + QH);
  u16* kt     = (u16*)(ws + KT);
  u16* vt     = (u16*)(ws + VT);
  u16* ctx    = (u16*)(ws + CTX);
  float* hF   = (float*)(ws + HBUF);
  float* sp0  = (float*)(ws + SP0);
  u16* ffn_mid = (u16*)(ws + FFN_MID);

  // ---- prep: all weight transposes + enc cvt + LN1, one launch ----
  PrepArgs pa;
  pa.w[0] = qkv_w;    pa.wt[0] = wt_qkv;     pa.K[0] = 1024; pa.N[0] = 3072; pa.cum[0] = 3072;
  pa.w[1] = attn_o_w; pa.wt[1] = wt_attn_o;  pa.K[1] = 1024; pa.N[1] = 1024; pa.cum[1] = 4096;
  pa.w[2] = q_w;      pa.wt[2] = wt_q;       pa.K[2] = 1024; pa.N[2] = 1024; pa.cum[2] = 5120;
  pa.w[3] = kv_w;     pa.wt[3] = wt_kv;      pa.K[3] = 1024; pa.N[3] = 2048; pa.cum[3] = 7168;
  pa.w[4] = ca_o_w;   pa.wt[4] = wt_ca_o;    pa.K[4] = 1024; pa.N[4] = 1024; pa.cum[4] = 8192;
  pa.w[5] = ffn_in_w; pa.wt[5] = wt_ffn_in;  pa.K[5] = 1024; pa.N[5] = 4096; pa.cum[5] = 12288;
  pa.w[6] = ffn_out_w;pa.wt[6] = wt_ffn_out; pa.K[6] = 4096; pa.N[6] = 1024; pa.cum[6] = 16384;
  pa.enc = enc; pa.enc_bf = enc_bf;
  pa.hid = hidden; pa.ln1w = ln1w; pa.ln1b = ln1b; pa.xln = xln;
  prep_kernel<<<24576, 256, 0, stream>>>(pa);

  // ---- self-attention ----
  gemm_big<128, 128, 1><<<dim3(24, 32), 512, 0, stream>>>(xln, wt_qkv, qkv_b, qh, kt, vt, 3072, 1024);
  flash_attn<<<dim3(8, 128), 256, 0, stream>>>(qh, kt, vt, nullptr, ctx, 1);
  gemm_n1024<64, 128, 0><<<dim3(8, 64), 512, 0, stream>>>(ctx, wt_attn_o, attn_o_b, nullptr, sp0, nullptr, 1024);
  ln_red1_kernel<<<4096, 256, 0, stream>>>(sp0, attn_o_b, hidden, ln2w, ln2b, hF, xln);

  // ---- cross-attention ----
  gemm_n1024<64, 128, 1><<<dim3(8, 64), 512, 0, stream>>>(xln, wt_q, q_b, nullptr, nullptr, qh, 1024);
  gemm_big<128, 128, 3><<<dim3(16, 32), 512, 0, stream>>>(enc_bf, wt_kv, kv_b, nullptr, kt, vt, 2048, 1024);
  flash_attn<<<dim3(8, 128), 256, 0, stream>>>(qh, kt, vt, encm, ctx, 0);
  gemm_n1024<64, 128, 0><<<dim3(8, 64), 512, 0, stream>>>(ctx, wt_ca_o, ca_o_b, nullptr, sp0, nullptr, 1024);
  ln_red1_kernel<<<4096, 256, 0, stream>>>(sp0, ca_o_b, hF, ln3w, ln3b, hF, xln);

  // ---- FFN ----
  gemm_big<128, 128, 0><<<dim3(32, 32), 512, 0, stream>>>(xln, wt_ffn_in, ffn_in_b, ffn_mid, nullptr, nullptr, 4096, 1024);
  gemm_n1024<64, 128, 2><<<dim3(8, 64), 512, 0, stream>>>(ffn_mid, wt_ffn_out, ffn_out_b, hF, (float*)d_out, nullptr, 4096);
}